// Round 1
// baseline (830.668 us; speedup 1.0000x reference)
//
#include <hip/hip_runtime.h>
#include <hip/hip_bf16.h>

#define IN_F 128
#define H_F 64
#define C_F 16

// ---------------- degree + norm ----------------
__global__ void k_degrees(const int* __restrict__ src, const int* __restrict__ dst,
                          float* __restrict__ deg_out, float* __restrict__ deg_in, int E) {
    int e = blockIdx.x * 256 + threadIdx.x;
    if (e < E) {
        atomicAdd(&deg_out[src[e]], 1.0f);
        atomicAdd(&deg_in[dst[e]], 1.0f);
    }
}

__global__ void k_norms(float* __restrict__ deg_out, float* __restrict__ deg_in, int N) {
    int n = blockIdx.x * 256 + threadIdx.x;
    if (n < N) {
        deg_out[n] = 1.0f / sqrtf(fmaxf(deg_out[n], 1.0f));
        deg_in[n]  = 1.0f / sqrtf(fmaxf(deg_in[n], 1.0f));
    }
}

// ---------------- layer 1 GEMM: X1 = (in_feat * norm_out) @ W1, [N,64] ----------------
__global__ __launch_bounds__(256) void k_gemm1(const float* __restrict__ in_feat,
                                               const float* __restrict__ W1,
                                               const float* __restrict__ norm_out,
                                               float* __restrict__ X1, int N) {
    __shared__ float Wl[IN_F * H_F];  // 32 KiB
    for (int i = threadIdx.x; i < IN_F * H_F; i += 256) Wl[i] = W1[i];
    __syncthreads();
    const int j   = threadIdx.x & 63;
    const int sub = threadIdx.x >> 6;      // 0..3
    const int base = blockIdx.x * 64;      // 64 nodes per block
    for (int s = sub; s < 64; s += 4) {
        int n = base + s;
        if (n >= N) break;
        const float* row = in_feat + (size_t)n * IN_F;
        float acc = 0.0f;
#pragma unroll 8
        for (int k = 0; k < IN_F; ++k) acc += row[k] * Wl[k * H_F + j];
        X1[(size_t)n * H_F + j] = acc * norm_out[n];
    }
}

// ---------------- edge scatter-add, 64 feats ----------------
__global__ void k_scatter64(const float* __restrict__ X, const int* __restrict__ src,
                            const int* __restrict__ dst, float* __restrict__ agg, long total) {
    long idx = (long)blockIdx.x * 256 + threadIdx.x;
    if (idx >= total) return;
    int e = (int)(idx >> 6);
    int j = (int)(idx & 63);
    int s = src[e], d = dst[e];
    atomicAdd(&agg[(size_t)d * 64 + j], X[(size_t)s * 64 + j]);
}

// ---------------- h = relu(agg1 * norm_in + b1) ----------------
__global__ void k_apply1(const float* __restrict__ agg, const float* __restrict__ norm_in,
                         const float* __restrict__ b1, float* __restrict__ h, int N) {
    long i = (long)blockIdx.x * 256 + threadIdx.x;
    long total = (long)N * H_F;
    if (i >= total) return;
    int n = (int)(i >> 6);
    int j = (int)(i & 63);
    float v = agg[i] * norm_in[n] + b1[j];
    h[i] = v > 0.0f ? v : 0.0f;
}

// ---------------- layer 2 GEMM: X2 = (h * norm_out) @ W2, [N,16] ----------------
__global__ __launch_bounds__(256) void k_gemm2(const float* __restrict__ h,
                                               const float* __restrict__ W2,
                                               const float* __restrict__ norm_out,
                                               float* __restrict__ X2, int N) {
    __shared__ float Wl[H_F * C_F];  // 4 KiB
    for (int i = threadIdx.x; i < H_F * C_F; i += 256) Wl[i] = W2[i];
    __syncthreads();
    const int j   = threadIdx.x & 15;
    const int sub = threadIdx.x >> 4;      // 0..15
    const int base = blockIdx.x * 64;
    for (int s = sub; s < 64; s += 16) {
        int n = base + s;
        if (n >= N) continue;
        const float* row = h + (size_t)n * H_F;
        float acc = 0.0f;
#pragma unroll
        for (int k = 0; k < H_F; ++k) acc += row[k] * Wl[k * C_F + j];
        X2[(size_t)n * C_F + j] = acc * norm_out[n];
    }
}

// ---------------- edge scatter-add, 16 feats ----------------
__global__ void k_scatter16(const float* __restrict__ X, const int* __restrict__ src,
                            const int* __restrict__ dst, float* __restrict__ agg, long total) {
    long idx = (long)blockIdx.x * 256 + threadIdx.x;
    if (idx >= total) return;
    int e = (int)(idx >> 4);
    int j = (int)(idx & 15);
    int s = src[e], d = dst[e];
    atomicAdd(&agg[(size_t)d * C_F + j], X[(size_t)s * C_F + j]);
}

// ---------------- partial column sums of agg2 * norm_in ----------------
__global__ __launch_bounds__(256) void k_reduce(const float* __restrict__ agg2,
                                                const float* __restrict__ norm_in,
                                                float* __restrict__ partials, int N) {
    const int j = threadIdx.x & 15;
    const int s = threadIdx.x >> 4;   // 0..15
    float acc = 0.0f;
    for (int n = blockIdx.x * 16 + s; n < N; n += gridDim.x * 16)
        acc += agg2[(size_t)n * C_F + j] * norm_in[n];
    __shared__ float lds[16][C_F + 1];
    lds[s][j] = acc;
    __syncthreads();
    if (threadIdx.x < C_F) {
        float t = 0.0f;
#pragma unroll
        for (int k = 0; k < 16; ++k) t += lds[k][threadIdx.x];
        partials[blockIdx.x * C_F + threadIdx.x] = t;
    }
}

// ---------------- final: out[j] = sum(partials)/N + b2[j] (deterministic f64) ----------------
__global__ void k_final(const float* __restrict__ partials, const float* __restrict__ b2,
                        float* __restrict__ out, int nPart, int N) {
    int j = threadIdx.x;
    if (j < C_F) {
        double sum = 0.0;
        for (int p = 0; p < nPart; ++p) sum += (double)partials[p * C_F + j];
        out[j] = (float)(sum / (double)N + (double)b2[j]);
    }
}

extern "C" void kernel_launch(void* const* d_in, const int* in_sizes, int n_in,
                              void* d_out, int out_size, void* d_ws, size_t ws_size,
                              hipStream_t stream) {
    const float* in_feat = (const float*)d_in[0];
    const int*   src     = (const int*)d_in[1];
    const int*   dst     = (const int*)d_in[2];
    const float* W1      = (const float*)d_in[3];
    const float* b1      = (const float*)d_in[4];
    const float* W2      = (const float*)d_in[5];
    const float* b2      = (const float*)d_in[6];
    float* out = (float*)d_out;

    const int N = in_sizes[0] / IN_F;   // 100000
    const int E = in_sizes[1];          // 1600000
    const int NPART = 256;

    float* ws = (float*)d_ws;
    float* norm_out = ws;                           // N  (deg_out -> norm_out)
    float* norm_in  = ws + (size_t)N;               // N  (deg_in  -> norm_in)
    float* bufA     = ws + 2 * (size_t)N;           // 64N : X1, then h
    float* bufB     = bufA + 64 * (size_t)N;        // 64N : agg1, then X2 (16N)
    float* agg2     = bufB + 64 * (size_t)N;        // 16N
    float* partials = agg2 + 16 * (size_t)N;        // NPART*16

    // zero everything that is read-before-write (ws is NOT re-poisoned between replays)
    hipMemsetAsync(ws, 0, 2 * (size_t)N * sizeof(float), stream);                       // degrees
    hipMemsetAsync(bufB, 0, (80 * (size_t)N + NPART * C_F) * sizeof(float), stream);    // agg1+agg2+partials

    k_degrees<<<(E + 255) / 256, 256, 0, stream>>>(src, dst, norm_out, norm_in, E);
    k_norms  <<<(N + 255) / 256, 256, 0, stream>>>(norm_out, norm_in, N);

    k_gemm1<<<(N + 63) / 64, 256, 0, stream>>>(in_feat, W1, norm_out, bufA, N);

    long tot1 = (long)E * 64;
    k_scatter64<<<(int)((tot1 + 255) / 256), 256, 0, stream>>>(bufA, src, dst, bufB, tot1);

    long totN1 = (long)N * H_F;
    k_apply1<<<(int)((totN1 + 255) / 256), 256, 0, stream>>>(bufB, norm_in, b1, bufA, N);

    k_gemm2<<<(N + 63) / 64, 256, 0, stream>>>(bufA, W2, norm_out, bufB, N);

    long tot2 = (long)E * 16;
    k_scatter16<<<(int)((tot2 + 255) / 256), 256, 0, stream>>>(bufB, src, dst, agg2, tot2);

    k_reduce<<<NPART, 256, 0, stream>>>(agg2, norm_in, partials, N);
    k_final<<<1, 64, 0, stream>>>(partials, b2, out, NPART, N);
}

// Round 2
// 634.275 us; speedup vs baseline: 1.3096x; 1.3096x over previous
//
#include <hip/hip_runtime.h>
#include <hip/hip_bf16.h>

#define IN_F 128
#define H_F 64
#define C_F 16

// ---------------- degree (int) ----------------
__global__ void k_degrees(const int* __restrict__ src, const int* __restrict__ dst,
                          int* __restrict__ degi_out, int* __restrict__ degi_in, int E) {
    int e = blockIdx.x * 256 + threadIdx.x;
    if (e < E) {
        atomicAdd(&degi_out[src[e]], 1);
        atomicAdd(&degi_in[dst[e]], 1);
    }
}

__global__ void k_norms(const int* __restrict__ degi_out, const int* __restrict__ degi_in,
                        float* __restrict__ norm_out, float* __restrict__ norm_in, int N) {
    int n = blockIdx.x * 256 + threadIdx.x;
    if (n < N) {
        norm_out[n] = 1.0f / sqrtf((float)max(degi_out[n], 1));
        norm_in[n]  = 1.0f / sqrtf((float)max(degi_in[n], 1));
    }
}

// ---------------- exclusive scan of degi_in -> offsets (3 kernels) ----------------
__global__ __launch_bounds__(256) void k_scan_partial(const int* __restrict__ degi,
                                                      int* __restrict__ blockSums, int N) {
    __shared__ int s[256];
    int t = threadIdx.x;
    int i = blockIdx.x * 256 + t;
    s[t] = (i < N) ? degi[i] : 0;
    __syncthreads();
    for (int off = 128; off; off >>= 1) {
        if (t < off) s[t] += s[t + off];
        __syncthreads();
    }
    if (t == 0) blockSums[blockIdx.x] = s[0];
}

__global__ __launch_bounds__(512) void k_scan_block(const int* __restrict__ blockSums,
                                                    int* __restrict__ blockOffs, int nb) {
    __shared__ int s[512];
    int t = threadIdx.x;
    int v = (t < nb) ? blockSums[t] : 0;
    s[t] = v;
    __syncthreads();
    for (int off = 1; off < 512; off <<= 1) {
        int x = (t >= off) ? s[t - off] : 0;
        __syncthreads();
        s[t] += x;
        __syncthreads();
    }
    if (t < nb) blockOffs[t] = s[t] - v;   // exclusive
}

__global__ __launch_bounds__(256) void k_scan_final(const int* __restrict__ degi,
                                                    const int* __restrict__ blockOffs,
                                                    int* __restrict__ offsets,
                                                    int* __restrict__ cursor, int N, int E) {
    __shared__ int s[256];
    int t = threadIdx.x;
    int i = blockIdx.x * 256 + t;
    int v = (i < N) ? degi[i] : 0;
    s[t] = v;
    __syncthreads();
    for (int off = 1; off < 256; off <<= 1) {
        int x = (t >= off) ? s[t - off] : 0;
        __syncthreads();
        s[t] += x;
        __syncthreads();
    }
    int excl = blockOffs[blockIdx.x] + s[t] - v;
    if (i < N) {
        offsets[i] = excl;
        cursor[i]  = excl;
        if (i == N - 1) offsets[N] = E;
    }
}

// ---------------- CSR placement: sorted_src grouped by dst ----------------
__global__ void k_place(const int* __restrict__ src, const int* __restrict__ dst,
                        int* __restrict__ cursor, int* __restrict__ sorted_src, int E) {
    int e = blockIdx.x * 256 + threadIdx.x;
    if (e < E) {
        int pos = atomicAdd(&cursor[dst[e]], 1);
        sorted_src[pos] = src[e];
    }
}

// ---------------- layer 1 GEMM: X1 = (in_feat * norm_out) @ W1, [N,64] ----------------
__global__ __launch_bounds__(256) void k_gemm1(const float* __restrict__ in_feat,
                                               const float* __restrict__ W1,
                                               const float* __restrict__ norm_out,
                                               float* __restrict__ X1, int N) {
    __shared__ float Wl[IN_F * H_F];  // 32 KiB
    for (int i = threadIdx.x; i < IN_F * H_F; i += 256) Wl[i] = W1[i];
    __syncthreads();
    const int j   = threadIdx.x & 63;
    const int sub = threadIdx.x >> 6;      // 0..3
    const int base = blockIdx.x * 64;      // 64 nodes per block
    for (int s = sub; s < 64; s += 4) {
        int n = base + s;
        if (n >= N) break;
        const float* row = in_feat + (size_t)n * IN_F;
        float acc = 0.0f;
#pragma unroll 8
        for (int k = 0; k < IN_F; ++k) acc += row[k] * Wl[k * H_F + j];
        X1[(size_t)n * H_F + j] = acc * norm_out[n];
    }
}

// ---------------- fused: agg1 (CSR gather-sum) + relu/bias/norms + GEMM2 -> X2 [N,16] ----
__global__ __launch_bounds__(256) void k_agg1g2(const float* __restrict__ X1,
                                                const int* __restrict__ offsets,
                                                const int* __restrict__ sorted_src,
                                                const float* __restrict__ norm_in,
                                                const float* __restrict__ norm_out,
                                                const float* __restrict__ b1,
                                                const float* __restrict__ W2,
                                                float* __restrict__ X2, int N) {
    __shared__ float Wl[H_F * C_F];   // 4 KiB
    __shared__ float hl[4][H_F];
    for (int i = threadIdx.x; i < H_F * C_F; i += 256) Wl[i] = W2[i];
    __syncthreads();
    const int wave = threadIdx.x >> 6;
    const int j    = threadIdx.x & 63;
    const int n    = blockIdx.x * 4 + wave;
    float hval = 0.0f;
    if (n < N) {
        int s0 = offsets[n], s1 = offsets[n + 1];
        float acc = 0.0f;
        int k = s0;
        for (; k + 1 < s1; k += 2) {
            int sa = sorted_src[k], sb = sorted_src[k + 1];
            acc += X1[(size_t)sa * H_F + j];
            acc += X1[(size_t)sb * H_F + j];
        }
        if (k < s1) acc += X1[(size_t)sorted_src[k] * H_F + j];
        float v = acc * norm_in[n] + b1[j];
        hval = (v > 0.0f ? v : 0.0f) * norm_out[n];   // pre-scale for layer 2
    }
    hl[wave][j] = hval;
    __syncthreads();
    if (n < N) {
        const int c = j & 15, q = j >> 4;
        float p = 0.0f;
#pragma unroll
        for (int kk = 0; kk < 16; ++kk)
            p += hl[wave][q * 16 + kk] * Wl[(q * 16 + kk) * C_F + c];
        p += __shfl_xor(p, 16);
        p += __shfl_xor(p, 32);
        if (j < C_F) X2[(size_t)n * C_F + j] = p;
    }
}

// ---------------- layer 2 aggregation (CSR), fused norm_in -> agg2 [N,16] ----------------
__global__ __launch_bounds__(256) void k_agg2(const float* __restrict__ X2,
                                              const int* __restrict__ offsets,
                                              const int* __restrict__ sorted_src,
                                              const float* __restrict__ norm_in,
                                              float* __restrict__ agg2, int N) {
    const int wave = threadIdx.x >> 6;
    const int lane = threadIdx.x & 63;
    const int n = blockIdx.x * 4 + wave;
    if (n >= N) return;
    const int j = lane & 15, eo = lane >> 4;
    int s0 = offsets[n], s1 = offsets[n + 1];
    float acc = 0.0f;
    for (int k = s0 + eo; k < s1; k += 4)
        acc += X2[(size_t)sorted_src[k] * C_F + j];
    acc += __shfl_xor(acc, 16);
    acc += __shfl_xor(acc, 32);
    if (lane < C_F) agg2[(size_t)n * C_F + j] = acc * norm_in[n];
}

// ---------------- partial column sums of agg2 ----------------
__global__ __launch_bounds__(256) void k_reduce(const float* __restrict__ agg2,
                                                float* __restrict__ partials, int N) {
    const int j = threadIdx.x & 15;
    const int s = threadIdx.x >> 4;   // 0..15
    float acc = 0.0f;
    for (int n = blockIdx.x * 16 + s; n < N; n += gridDim.x * 16)
        acc += agg2[(size_t)n * C_F + j];
    __shared__ float lds[16][C_F + 1];
    lds[s][j] = acc;
    __syncthreads();
    if (threadIdx.x < C_F) {
        float t = 0.0f;
#pragma unroll
        for (int k = 0; k < 16; ++k) t += lds[k][threadIdx.x];
        partials[blockIdx.x * C_F + threadIdx.x] = t;
    }
}

// ---------------- final: out[j] = sum(partials)/N + b2[j] (deterministic f64) ----------------
__global__ void k_final(const float* __restrict__ partials, const float* __restrict__ b2,
                        float* __restrict__ out, int nPart, int N) {
    int j = threadIdx.x;
    if (j < C_F) {
        double sum = 0.0;
        for (int p = 0; p < nPart; ++p) sum += (double)partials[p * C_F + j];
        out[j] = (float)(sum / (double)N + (double)b2[j]);
    }
}

extern "C" void kernel_launch(void* const* d_in, const int* in_sizes, int n_in,
                              void* d_out, int out_size, void* d_ws, size_t ws_size,
                              hipStream_t stream) {
    const float* in_feat = (const float*)d_in[0];
    const int*   src     = (const int*)d_in[1];
    const int*   dst     = (const int*)d_in[2];
    const float* W1      = (const float*)d_in[3];
    const float* b1      = (const float*)d_in[4];
    const float* W2      = (const float*)d_in[5];
    const float* b2      = (const float*)d_in[6];
    float* out = (float*)d_out;

    const int N = in_sizes[0] / IN_F;   // 100000
    const int E = in_sizes[1];          // 1600000
    const int NPART = 256;
    const int nScan = (N + 255) / 256;  // 391 (<= 512)

    // ---- workspace layout (all 4B units) ----
    int*   degi_out  = (int*)d_ws;                       // N
    int*   degi_in   = degi_out + N;                     // N
    float* norm_out  = (float*)(degi_in + N);            // N
    float* norm_in   = norm_out + N;                     // N
    int*   offsets   = (int*)(norm_in + N);              // N+1
    int*   cursor    = offsets + N + 1;                  // N
    int*   blockSums = cursor + N;                       // 512
    int*   blockOffs = blockSums + 512;                  // 512
    int*   sorted_src= blockOffs + 512;                  // E
    float* X1        = (float*)(sorted_src + E);         // 64N
    float* X2        = X1 + 64 * (size_t)N;              // 16N
    float* agg2      = X2 + 16 * (size_t)N;              // 16N
    float* partials  = agg2 + 16 * (size_t)N;            // NPART*16

    // only degrees are read-before-write
    hipMemsetAsync(degi_out, 0, 2 * (size_t)N * sizeof(int), stream);

    k_degrees<<<(E + 255) / 256, 256, 0, stream>>>(src, dst, degi_out, degi_in, E);
    k_norms  <<<(N + 255) / 256, 256, 0, stream>>>(degi_out, degi_in, norm_out, norm_in, N);

    k_scan_partial<<<nScan, 256, 0, stream>>>(degi_in, blockSums, N);
    k_scan_block  <<<1, 512, 0, stream>>>(blockSums, blockOffs, nScan);
    k_scan_final  <<<nScan, 256, 0, stream>>>(degi_in, blockOffs, offsets, cursor, N, E);

    k_place<<<(E + 255) / 256, 256, 0, stream>>>(src, dst, cursor, sorted_src, E);

    k_gemm1<<<(N + 63) / 64, 256, 0, stream>>>(in_feat, W1, norm_out, X1, N);

    k_agg1g2<<<(N + 3) / 4, 256, 0, stream>>>(X1, offsets, sorted_src, norm_in, norm_out,
                                              b1, W2, X2, N);

    k_agg2<<<(N + 3) / 4, 256, 0, stream>>>(X2, offsets, sorted_src, norm_in, agg2, N);

    k_reduce<<<NPART, 256, 0, stream>>>(agg2, partials, N);
    k_final<<<1, 64, 0, stream>>>(partials, b2, out, NPART, N);
}

// Round 3
// 524.323 us; speedup vs baseline: 1.5843x; 1.2097x over previous
//
#include <hip/hip_runtime.h>
#include <hip/hip_bf16.h>

#define IN_F 128
#define H_F 64
#define C_F 16

// ---------------- degree (int) ----------------
__global__ void k_degrees(const int* __restrict__ src, const int* __restrict__ dst,
                          int* __restrict__ degi_out, int* __restrict__ degi_in, int E) {
    int e = blockIdx.x * 256 + threadIdx.x;
    if (e < E) {
        atomicAdd(&degi_out[src[e]], 1);
        atomicAdd(&degi_in[dst[e]], 1);
    }
}

// ---------------- exclusive scan of degi_in -> offsets (+ norms fused) ----------------
__global__ __launch_bounds__(256) void k_scan_partial(const int* __restrict__ degi,
                                                      int* __restrict__ blockSums, int N) {
    __shared__ int s[256];
    int t = threadIdx.x;
    int i = blockIdx.x * 256 + t;
    s[t] = (i < N) ? degi[i] : 0;
    __syncthreads();
    for (int off = 128; off; off >>= 1) {
        if (t < off) s[t] += s[t + off];
        __syncthreads();
    }
    if (t == 0) blockSums[blockIdx.x] = s[0];
}

__global__ __launch_bounds__(512) void k_scan_block(const int* __restrict__ blockSums,
                                                    int* __restrict__ blockOffs, int nb) {
    __shared__ int s[512];
    int t = threadIdx.x;
    int v = (t < nb) ? blockSums[t] : 0;
    s[t] = v;
    __syncthreads();
    for (int off = 1; off < 512; off <<= 1) {
        int x = (t >= off) ? s[t - off] : 0;
        __syncthreads();
        s[t] += x;
        __syncthreads();
    }
    if (t < nb) blockOffs[t] = s[t] - v;   // exclusive
}

__global__ __launch_bounds__(256) void k_scan_final(const int* __restrict__ degi,
                                                    const int* __restrict__ degi_out,
                                                    const int* __restrict__ blockOffs,
                                                    int* __restrict__ offsets,
                                                    int* __restrict__ cursor,
                                                    float* __restrict__ norm_out,
                                                    float* __restrict__ norm_in,
                                                    int N, int E) {
    __shared__ int s[256];
    int t = threadIdx.x;
    int i = blockIdx.x * 256 + t;
    int v = (i < N) ? degi[i] : 0;
    s[t] = v;
    __syncthreads();
    for (int off = 1; off < 256; off <<= 1) {
        int x = (t >= off) ? s[t - off] : 0;
        __syncthreads();
        s[t] += x;
        __syncthreads();
    }
    int excl = blockOffs[blockIdx.x] + s[t] - v;
    if (i < N) {
        offsets[i] = excl;
        cursor[i]  = excl;
        if (i == N - 1) offsets[N] = E;
        norm_in[i]  = 1.0f / sqrtf((float)max(v, 1));
        norm_out[i] = 1.0f / sqrtf((float)max(degi_out[i], 1));
    }
}

// ---------------- CSR placement: sorted_src grouped by dst ----------------
__global__ void k_place(const int* __restrict__ src, const int* __restrict__ dst,
                        int* __restrict__ cursor, int* __restrict__ sorted_src, int E) {
    int e = blockIdx.x * 256 + threadIdx.x;
    if (e < E) {
        int pos = atomicAdd(&cursor[dst[e]], 1);
        sorted_src[pos] = src[e];
    }
}

// ---------------- layer 1 GEMM: X1 = (in_feat @ W1) * norm_out, [N,64] ----------------
// 256 threads, 64 nodes/block. W1 (32KB) + A-tile (33KB) in LDS.
// Thread (r,c): r=t>>4 node group (4 nodes), c=t&15 output group (4 outputs).
__global__ __launch_bounds__(256) void k_gemm1(const float* __restrict__ in_feat,
                                               const float* __restrict__ W1,
                                               const float* __restrict__ norm_out,
                                               float* __restrict__ X1, int N) {
    __shared__ float Wl[IN_F][H_F];       // [k][j], 32 KB
    __shared__ float Al[64][IN_F + 4];    // +4 pad, 33 KB
    const int t = threadIdx.x;
    const int base = blockIdx.x * 64;

    // stage W1: 8192 floats = 2048 float4
    for (int i = t; i < IN_F * H_F / 4; i += 256)
        ((float4*)&Wl[0][0])[i] = ((const float4*)W1)[i];
    // stage A-tile: 64 rows x 128 floats = 2048 float4
    for (int i = t; i < 64 * IN_F / 4; i += 256) {
        int n = i >> 5;            // 32 float4 per row
        int k4 = i & 31;
        int gn = base + n;
        float4 v = make_float4(0.f, 0.f, 0.f, 0.f);
        if (gn < N) v = ((const float4*)(in_feat + (size_t)gn * IN_F))[k4];
        *(float4*)&Al[n][k4 * 4] = v;
    }
    __syncthreads();

    const int c4 = (t & 15) * 4;
    const int r4 = (t >> 4) * 4;
    float acc[4][4] = {};
#pragma unroll 4
    for (int k = 0; k < IN_F; k += 4) {
        float4 w0 = *(const float4*)&Wl[k + 0][c4];
        float4 w1 = *(const float4*)&Wl[k + 1][c4];
        float4 w2 = *(const float4*)&Wl[k + 2][c4];
        float4 w3 = *(const float4*)&Wl[k + 3][c4];
        const float* wp0 = (const float*)&w0;
        const float* wp1 = (const float*)&w1;
        const float* wp2 = (const float*)&w2;
        const float* wp3 = (const float*)&w3;
#pragma unroll
        for (int i = 0; i < 4; ++i) {
            float4 a = *(const float4*)&Al[r4 + i][k];
#pragma unroll
            for (int jj = 0; jj < 4; ++jj)
                acc[i][jj] = fmaf(a.x, wp0[jj],
                             fmaf(a.y, wp1[jj],
                             fmaf(a.z, wp2[jj],
                             fmaf(a.w, wp3[jj], acc[i][jj]))));
        }
    }
#pragma unroll
    for (int i = 0; i < 4; ++i) {
        int n = base + r4 + i;
        if (n < N) {
            float no = norm_out[n];
            float4 o = make_float4(acc[i][0] * no, acc[i][1] * no,
                                   acc[i][2] * no, acc[i][3] * no);
            *(float4*)&X1[(size_t)n * H_F + c4] = o;
        }
    }
}

// ---------------- fused: agg1 (CSR gather-sum) + relu/bias/norms + GEMM2 -> X2 [N,16] ----
__global__ __launch_bounds__(256) void k_agg1g2(const float* __restrict__ X1,
                                                const int* __restrict__ offsets,
                                                const int* __restrict__ sorted_src,
                                                const float* __restrict__ norm_in,
                                                const float* __restrict__ norm_out,
                                                const float* __restrict__ b1,
                                                const float* __restrict__ W2,
                                                float* __restrict__ X2, int N) {
    __shared__ float Wl[H_F * C_F];   // 4 KiB
    __shared__ float hl[4][H_F];
    for (int i = threadIdx.x; i < H_F * C_F; i += 256) Wl[i] = W2[i];
    __syncthreads();
    const int wave = threadIdx.x >> 6;
    const int j    = threadIdx.x & 63;
    const int n    = blockIdx.x * 4 + wave;
    float hval = 0.0f;
    if (n < N) {
        int s0 = offsets[n], s1 = offsets[n + 1];
        float acc = 0.0f;
        int k = s0;
        for (; k + 1 < s1; k += 2) {
            int sa = sorted_src[k], sb = sorted_src[k + 1];
            acc += X1[(size_t)sa * H_F + j];
            acc += X1[(size_t)sb * H_F + j];
        }
        if (k < s1) acc += X1[(size_t)sorted_src[k] * H_F + j];
        float v = acc * norm_in[n] + b1[j];
        hval = (v > 0.0f ? v : 0.0f) * norm_out[n];   // pre-scale for layer 2
    }
    hl[wave][j] = hval;
    __syncthreads();
    if (n < N) {
        const int c = j & 15, q = j >> 4;
        float p = 0.0f;
#pragma unroll
        for (int kk = 0; kk < 16; ++kk)
            p += hl[wave][q * 16 + kk] * Wl[(q * 16 + kk) * C_F + c];
        p += __shfl_xor(p, 16);
        p += __shfl_xor(p, 32);
        if (j < C_F) X2[(size_t)n * C_F + j] = p;
    }
}

// ---------------- layer 2 aggregation (CSR), fused norm_in -> agg2 [N,16] ----------------
__global__ __launch_bounds__(256) void k_agg2(const float* __restrict__ X2,
                                              const int* __restrict__ offsets,
                                              const int* __restrict__ sorted_src,
                                              const float* __restrict__ norm_in,
                                              float* __restrict__ agg2, int N) {
    const int wave = threadIdx.x >> 6;
    const int lane = threadIdx.x & 63;
    const int n = blockIdx.x * 4 + wave;
    if (n >= N) return;
    const int j = lane & 15, eo = lane >> 4;
    int s0 = offsets[n], s1 = offsets[n + 1];
    float acc = 0.0f;
    for (int k = s0 + eo; k < s1; k += 4)
        acc += X2[(size_t)sorted_src[k] * C_F + j];
    acc += __shfl_xor(acc, 16);
    acc += __shfl_xor(acc, 32);
    if (lane < C_F) agg2[(size_t)n * C_F + j] = acc * norm_in[n];
}

// ---------------- partial column sums of agg2 ----------------
__global__ __launch_bounds__(256) void k_reduce(const float* __restrict__ agg2,
                                                float* __restrict__ partials, int N) {
    const int j = threadIdx.x & 15;
    const int s = threadIdx.x >> 4;   // 0..15
    float acc = 0.0f;
    for (int n = blockIdx.x * 16 + s; n < N; n += gridDim.x * 16)
        acc += agg2[(size_t)n * C_F + j];
    __shared__ float lds[16][C_F + 1];
    lds[s][j] = acc;
    __syncthreads();
    if (threadIdx.x < C_F) {
        float t = 0.0f;
#pragma unroll
        for (int k = 0; k < 16; ++k) t += lds[k][threadIdx.x];
        partials[blockIdx.x * C_F + threadIdx.x] = t;
    }
}

// ---------------- final: out[j] = sum(partials)/N + b2[j] (deterministic f64) ----------------
__global__ void k_final(const float* __restrict__ partials, const float* __restrict__ b2,
                        float* __restrict__ out, int nPart, int N) {
    int j = threadIdx.x;
    if (j < C_F) {
        double sum = 0.0;
        for (int p = 0; p < nPart; ++p) sum += (double)partials[p * C_F + j];
        out[j] = (float)(sum / (double)N + (double)b2[j]);
    }
}

extern "C" void kernel_launch(void* const* d_in, const int* in_sizes, int n_in,
                              void* d_out, int out_size, void* d_ws, size_t ws_size,
                              hipStream_t stream) {
    const float* in_feat = (const float*)d_in[0];
    const int*   src     = (const int*)d_in[1];
    const int*   dst     = (const int*)d_in[2];
    const float* W1      = (const float*)d_in[3];
    const float* b1      = (const float*)d_in[4];
    const float* W2      = (const float*)d_in[5];
    const float* b2      = (const float*)d_in[6];
    float* out = (float*)d_out;

    const int N = in_sizes[0] / IN_F;   // 100000
    const int E = in_sizes[1];          // 1600000
    const int NPART = 256;
    const int nScan = (N + 255) / 256;  // 391 (<= 512)

    // ---- workspace layout (all 4B units) ----
    int*   degi_out  = (int*)d_ws;                       // N
    int*   degi_in   = degi_out + N;                     // N
    float* norm_out  = (float*)(degi_in + N);            // N
    float* norm_in   = norm_out + N;                     // N
    int*   offsets   = (int*)(norm_in + N);              // N+1
    int*   cursor    = offsets + N + 1;                  // N
    int*   blockSums = cursor + N;                       // 512
    int*   blockOffs = blockSums + 512;                  // 512
    int*   sorted_src= blockOffs + 512;                  // E
    float* X1        = (float*)(sorted_src + E);         // 64N
    float* X2        = X1 + 64 * (size_t)N;              // 16N
    float* agg2      = X2 + 16 * (size_t)N;              // 16N
    float* partials  = agg2 + 16 * (size_t)N;            // NPART*16

    // only degrees are read-before-write
    hipMemsetAsync(degi_out, 0, 2 * (size_t)N * sizeof(int), stream);

    k_degrees<<<(E + 255) / 256, 256, 0, stream>>>(src, dst, degi_out, degi_in, E);

    k_scan_partial<<<nScan, 256, 0, stream>>>(degi_in, blockSums, N);
    k_scan_block  <<<1, 512, 0, stream>>>(blockSums, blockOffs, nScan);
    k_scan_final  <<<nScan, 256, 0, stream>>>(degi_in, degi_out, blockOffs, offsets, cursor,
                                              norm_out, norm_in, N, E);

    k_place<<<(E + 255) / 256, 256, 0, stream>>>(src, dst, cursor, sorted_src, E);

    k_gemm1<<<(N + 63) / 64, 256, 0, stream>>>(in_feat, W1, norm_out, X1, N);

    k_agg1g2<<<(N + 3) / 4, 256, 0, stream>>>(X1, offsets, sorted_src, norm_in, norm_out,
                                              b1, W2, X2, N);

    k_agg2<<<(N + 3) / 4, 256, 0, stream>>>(X2, offsets, sorted_src, norm_in, agg2, N);

    k_reduce<<<NPART, 256, 0, stream>>>(agg2, partials, N);
    k_final<<<1, 64, 0, stream>>>(partials, b2, out, NPART, N);
}

// Round 4
// 503.419 us; speedup vs baseline: 1.6501x; 1.0415x over previous
//
#include <hip/hip_runtime.h>
#include <hip/hip_bf16.h>
#include <hip/hip_fp16.h>

#define IN_F 128
#define H_F 64
#define C_F 16
#define NB_AGG 1024

// ---------------- degree (int) ----------------
__global__ void k_degrees(const int* __restrict__ src, const int* __restrict__ dst,
                          int* __restrict__ degi_out, int* __restrict__ degi_in, int E) {
    int e = blockIdx.x * 256 + threadIdx.x;
    if (e < E) {
        atomicAdd(&degi_out[src[e]], 1);
        atomicAdd(&degi_in[dst[e]], 1);
    }
}

// ---------------- exclusive scan of degi_in -> offsets (+ norms fused) ----------------
__global__ __launch_bounds__(256) void k_scan_partial(const int* __restrict__ degi,
                                                      int* __restrict__ blockSums, int N) {
    __shared__ int s[256];
    int t = threadIdx.x;
    int i = blockIdx.x * 256 + t;
    s[t] = (i < N) ? degi[i] : 0;
    __syncthreads();
    for (int off = 128; off; off >>= 1) {
        if (t < off) s[t] += s[t + off];
        __syncthreads();
    }
    if (t == 0) blockSums[blockIdx.x] = s[0];
}

__global__ __launch_bounds__(512) void k_scan_block(const int* __restrict__ blockSums,
                                                    int* __restrict__ blockOffs, int nb) {
    __shared__ int s[512];
    int t = threadIdx.x;
    int v = (t < nb) ? blockSums[t] : 0;
    s[t] = v;
    __syncthreads();
    for (int off = 1; off < 512; off <<= 1) {
        int x = (t >= off) ? s[t - off] : 0;
        __syncthreads();
        s[t] += x;
        __syncthreads();
    }
    if (t < nb) blockOffs[t] = s[t] - v;   // exclusive
}

__global__ __launch_bounds__(256) void k_scan_final(const int* __restrict__ degi,
                                                    const int* __restrict__ degi_out,
                                                    const int* __restrict__ blockOffs,
                                                    int* __restrict__ offsets,
                                                    int* __restrict__ cursor,
                                                    float* __restrict__ norm_out,
                                                    float* __restrict__ norm_in,
                                                    int N, int E) {
    __shared__ int s[256];
    int t = threadIdx.x;
    int i = blockIdx.x * 256 + t;
    int v = (i < N) ? degi[i] : 0;
    s[t] = v;
    __syncthreads();
    for (int off = 1; off < 256; off <<= 1) {
        int x = (t >= off) ? s[t - off] : 0;
        __syncthreads();
        s[t] += x;
        __syncthreads();
    }
    int excl = blockOffs[blockIdx.x] + s[t] - v;
    if (i < N) {
        offsets[i] = excl;
        cursor[i]  = excl;
        if (i == N - 1) offsets[N] = E;
        norm_in[i]  = 1.0f / sqrtf((float)max(v, 1));
        norm_out[i] = 1.0f / sqrtf((float)max(degi_out[i], 1));
    }
}

// ---------------- CSR placement (grouped by dst) + wsum[s] += norm_in[d] ----------------
__global__ void k_place(const int* __restrict__ src, const int* __restrict__ dst,
                        int* __restrict__ cursor, int* __restrict__ sorted_src,
                        const float* __restrict__ norm_in, float* __restrict__ wsum, int E) {
    int e = blockIdx.x * 256 + threadIdx.x;
    if (e < E) {
        int s = src[e], d = dst[e];
        int pos = atomicAdd(&cursor[d], 1);
        sorted_src[pos] = s;
        atomicAdd(&wsum[s], norm_in[d]);
    }
}

// ---------------- layer 1 GEMM: X1h = fp16((in_feat @ W1) * norm_out), [N,64] ----------
__global__ __launch_bounds__(256) void k_gemm1(const float* __restrict__ in_feat,
                                               const float* __restrict__ W1,
                                               const float* __restrict__ norm_out,
                                               __half* __restrict__ X1h, int N) {
    __shared__ float Wl[IN_F][H_F];       // 32 KB
    __shared__ float Al[64][IN_F + 4];    // 33 KB
    const int t = threadIdx.x;
    const int base = blockIdx.x * 64;

    for (int i = t; i < IN_F * H_F / 4; i += 256)
        ((float4*)&Wl[0][0])[i] = ((const float4*)W1)[i];
    for (int i = t; i < 64 * IN_F / 4; i += 256) {
        int n = i >> 5;
        int k4 = i & 31;
        int gn = base + n;
        float4 v = make_float4(0.f, 0.f, 0.f, 0.f);
        if (gn < N) v = ((const float4*)(in_feat + (size_t)gn * IN_F))[k4];
        *(float4*)&Al[n][k4 * 4] = v;
    }
    __syncthreads();

    const int c4 = (t & 15) * 4;
    const int r4 = (t >> 4) * 4;
    float acc[4][4] = {};
#pragma unroll 4
    for (int k = 0; k < IN_F; k += 4) {
        float4 w0 = *(const float4*)&Wl[k + 0][c4];
        float4 w1 = *(const float4*)&Wl[k + 1][c4];
        float4 w2 = *(const float4*)&Wl[k + 2][c4];
        float4 w3 = *(const float4*)&Wl[k + 3][c4];
        const float* wp0 = (const float*)&w0;
        const float* wp1 = (const float*)&w1;
        const float* wp2 = (const float*)&w2;
        const float* wp3 = (const float*)&w3;
#pragma unroll
        for (int i = 0; i < 4; ++i) {
            float4 a = *(const float4*)&Al[r4 + i][k];
#pragma unroll
            for (int jj = 0; jj < 4; ++jj)
                acc[i][jj] = fmaf(a.x, wp0[jj],
                             fmaf(a.y, wp1[jj],
                             fmaf(a.z, wp2[jj],
                             fmaf(a.w, wp3[jj], acc[i][jj]))));
        }
    }
#pragma unroll
    for (int i = 0; i < 4; ++i) {
        int n = base + r4 + i;
        if (n < N) {
            float no = norm_out[n];
            __half2 p0 = __floats2half2_rn(acc[i][0] * no, acc[i][1] * no);
            __half2 p1 = __floats2half2_rn(acc[i][2] * no, acc[i][3] * no);
            __half2* dp = (__half2*)&X1h[(size_t)n * H_F + c4];
            dp[0] = p0; dp[1] = p1;
        }
    }
}

// ---- fused: agg1 (CSR fp16 gather) + relu/bias + weighted column-sum -> partials[NB,64] ----
// hsum[j] = sum_n relu(agg1[n,j]*norm_in[n] + b1[j]) * norm_out[n] * wsum[n]
__global__ __launch_bounds__(256) void k_agg1h(const __half* __restrict__ X1h,
                                               const int* __restrict__ offsets,
                                               const int* __restrict__ sorted_src,
                                               const float* __restrict__ norm_in,
                                               const float* __restrict__ norm_out,
                                               const float* __restrict__ wsum,
                                               const float* __restrict__ b1,
                                               float* __restrict__ partials, int N) {
    const int wave = threadIdx.x >> 6;
    const int j    = threadIdx.x & 63;
    const float bj = b1[j];
    float hacc = 0.0f;
    for (int n = blockIdx.x * 4 + wave; n < N; n += NB_AGG * 4) {
        int s0 = offsets[n], s1 = offsets[n + 1];
        float acc = 0.0f;
        int k = s0;
        for (; k + 3 < s1; k += 4) {
            int sa = sorted_src[k], sb = sorted_src[k + 1];
            int sc = sorted_src[k + 2], sd = sorted_src[k + 3];
            float a0 = __half2float(X1h[(size_t)sa * H_F + j]);
            float a1 = __half2float(X1h[(size_t)sb * H_F + j]);
            float a2 = __half2float(X1h[(size_t)sc * H_F + j]);
            float a3 = __half2float(X1h[(size_t)sd * H_F + j]);
            acc += (a0 + a1) + (a2 + a3);
        }
        for (; k < s1; ++k)
            acc += __half2float(X1h[(size_t)sorted_src[k] * H_F + j]);
        float v = acc * norm_in[n] + bj;
        float h = v > 0.0f ? v : 0.0f;
        hacc = fmaf(h, norm_out[n] * wsum[n], hacc);
    }
    __shared__ float hl[4][64];
    hl[wave][j] = hacc;
    __syncthreads();
    if (wave == 0)
        partials[(size_t)blockIdx.x * 64 + j] =
            (hl[0][j] + hl[1][j]) + (hl[2][j] + hl[3][j]);
}

// ---------------- final: hsum (f64) -> out = hsum@W2/N + b2 ----------------
__global__ __launch_bounds__(256) void k_final(const float* __restrict__ partials,
                                               const float* __restrict__ W2,
                                               const float* __restrict__ b2,
                                               float* __restrict__ out, int N) {
    __shared__ double hs[4][64];
    const int sub = threadIdx.x >> 6;   // 0..3
    const int j   = threadIdx.x & 63;
    double s = 0.0;
    for (int p = sub; p < NB_AGG; p += 4)
        s += (double)partials[(size_t)p * 64 + j];
    hs[sub][j] = s;
    __syncthreads();
    if (threadIdx.x < C_F) {
        int c = threadIdx.x;
        double o = 0.0;
        for (int k = 0; k < 64; ++k) {
            double hk = hs[0][k] + hs[1][k] + hs[2][k] + hs[3][k];
            o += hk * (double)W2[k * C_F + c];
        }
        out[c] = (float)(o / (double)N + (double)b2[c]);
    }
}

extern "C" void kernel_launch(void* const* d_in, const int* in_sizes, int n_in,
                              void* d_out, int out_size, void* d_ws, size_t ws_size,
                              hipStream_t stream) {
    const float* in_feat = (const float*)d_in[0];
    const int*   src     = (const int*)d_in[1];
    const int*   dst     = (const int*)d_in[2];
    const float* W1      = (const float*)d_in[3];
    const float* b1      = (const float*)d_in[4];
    const float* W2      = (const float*)d_in[5];
    const float* b2      = (const float*)d_in[6];
    float* out = (float*)d_out;

    const int N = in_sizes[0] / IN_F;   // 100000
    const int E = in_sizes[1];          // 1600000
    const int nScan = (N + 255) / 256;  // 391 (<= 512)

    // ---- workspace layout (4B units) ----
    int*   degi_out  = (int*)d_ws;                       // N
    int*   degi_in   = degi_out + N;                     // N
    float* wsum      = (float*)(degi_in + N);            // N  (zeroed with degrees)
    float* norm_out  = wsum + N;                         // N
    float* norm_in   = norm_out + N;                     // N
    int*   offsets   = (int*)(norm_in + N);              // N+1
    int*   cursor    = offsets + N + 1;                  // N
    int*   blockSums = cursor + N;                       // 512
    int*   blockOffs = blockSums + 512;                  // 512 + 1 pad (8B-align X1h)
    int*   sorted_src= blockOffs + 513;                  // E
    __half* X1h      = (__half*)(sorted_src + E);        // 64N halves
    float* partials  = (float*)(X1h + 64 * (size_t)N);   // NB_AGG*64

    // degrees + wsum are read-before-write (contiguous 3N)
    hipMemsetAsync(degi_out, 0, 3 * (size_t)N * sizeof(int), stream);

    k_degrees<<<(E + 255) / 256, 256, 0, stream>>>(src, dst, degi_out, degi_in, E);

    k_scan_partial<<<nScan, 256, 0, stream>>>(degi_in, blockSums, N);
    k_scan_block  <<<1, 512, 0, stream>>>(blockSums, blockOffs, nScan);
    k_scan_final  <<<nScan, 256, 0, stream>>>(degi_in, degi_out, blockOffs, offsets, cursor,
                                              norm_out, norm_in, N, E);

    k_place<<<(E + 255) / 256, 256, 0, stream>>>(src, dst, cursor, sorted_src,
                                                 norm_in, wsum, E);

    k_gemm1<<<(N + 63) / 64, 256, 0, stream>>>(in_feat, W1, norm_out, X1h, N);

    k_agg1h<<<NB_AGG, 256, 0, stream>>>(X1h, offsets, sorted_src, norm_in, norm_out,
                                        wsum, b1, partials, N);

    k_final<<<1, 256, 0, stream>>>(partials, W2, b2, out, N);
}